// Round 6
// baseline (98.454 us; speedup 1.0000x reference)
//
#include <hip/hip_runtime.h>
#include <math.h>

// Problem constants: B=8, CIN=128, COUT=128, H=64, W=64, N=50000, NV=200000, M=800000
constexpr int CIN  = 128;
constexpr int COUT = 128;
constexpr int H    = 64;
constexpr int W    = 64;

typedef __attribute__((ext_vector_type(8))) short short8;   // 8 bf16 (4 VGPR)
typedef __attribute__((ext_vector_type(4))) float f32x4;

__device__ __forceinline__ float bf2f(unsigned short u) {
  union { unsigned i; float f; } c; c.i = (unsigned)u << 16; return c.f;
}
__device__ __forceinline__ float ubits(unsigned u) {
  union { unsigned i; float f; } c; c.i = u; return c.f;
}
__device__ __forceinline__ unsigned short f2bf(float f) {
  union { float f; unsigned i; } c; c.f = f;
  unsigned x = c.i;
  unsigned r = x + 0x7fffu + ((x >> 16) & 1u);   // RNE
  return (unsigned short)(r >> 16);
}

#define GLOAD_LDS16(g, l) __builtin_amdgcn_global_load_lds( \
  (const __attribute__((address_space(1))) unsigned int*)(g), \
  (__attribute__((address_space(3))) unsigned int*)(l), 16, 0, 0)

// ---------------------------------------------------------------------------
// Prep: (a) conv_w f32 [co][ci][3][3] -> Wt2 bf16 [q][co][ci] (k-major);
//       (b) per-point CSR meta: p0, p1, zero-fold flag
// ---------------------------------------------------------------------------
__global__ void prep_kernel(const float* __restrict__ w, unsigned short* __restrict__ wt2,
                            const int* __restrict__ aptr, const int* __restrict__ vptr,
                            int2* __restrict__ meta, int N) {
  int t = blockIdx.x * 256 + threadIdx.x;
  if (t < COUT * CIN) {
    float v[9];
#pragma unroll
    for (int q = 0; q < 9; ++q) v[q] = w[(size_t)t * 9 + q];
#pragma unroll
    for (int q = 0; q < 9; ++q) wt2[q * (COUT * CIN) + t] = f2bf(v[q]);
  }
  if (t < N) {
    int v0 = vptr[t], v1 = vptr[t + 1];
    int p0 = aptr[v0], p1 = aptr[v1];
    int e = (v1 == v0) ? 1 : 0;
    int prev = p0;
    for (int v = v0 + 1; v <= v1; ++v) {   // detect empty view segments
      int a = aptr[v];
      if (a == prev) e = 1;
      prev = a;
    }
    meta[t] = make_int2(p0, p1 | (e << 30));
  }
}

// ---------------------------------------------------------------------------
// Conv 3x3 SAME as implicit GEMM on MFMA bf16 (round-4 structure).
// Epilogue now writes channel-split half tables featA (co 0..63) / featB (64..127),
// each [32768 pixels][64 ch] bf16 = 4.19 MB (fits one XCD L2 for the pool).
// ---------------------------------------------------------------------------
__global__ __launch_bounds__(256, 2)
void conv_mfma_kernel(const float* __restrict__ in, const unsigned short* __restrict__ wt2,
                      const float* __restrict__ bias,
                      unsigned short* __restrict__ featA, unsigned short* __restrict__ featB) {
  __shared__ __align__(16) unsigned short sIn[3 * 66 * 64];  // 25344 B
  __shared__ __align__(16) unsigned short sW[128 * 64];      // 16384 B

  const int tid  = threadIdx.x;
  const int lane = tid & 63;
  const int wid  = tid >> 6;
  const int h0   = blockIdx.x;
  const int b    = blockIdx.y;
  const int wave_px = (wid >> 1) * 32;
  const int wave_co = (wid & 1) * 64;
  const int l15  = lane & 15;
  const int kk   = lane >> 4;

  char* sInc = (char*)sIn;
  char* sWc  = (char*)sW;

  f32x4 acc[2][4];
#pragma unroll
  for (int m = 0; m < 2; ++m)
#pragma unroll
    for (int n = 0; n < 4; ++n) acc[m][n] = (f32x4){0.f, 0.f, 0.f, 0.f};

  float bv[4];
#pragma unroll
  for (int n = 0; n < 4; ++n) bv[n] = bias[wave_co + n * 16 + l15];

  for (int i = tid; i < 3 * 64 * 2; i += 256) {   // zero pad columns wp=0,65
    int rr = i >> 7, rem = i & 127;
    int wp = (rem & 1) ? 65 : 0, ci = rem >> 1;
    int byte = rr * 8448 + wp * 128 + ci * 2;
    byte ^= ((wp & 7) << 4);
    *(unsigned short*)(sInc + byte) = 0;
  }

  int swd[4], swsrc[4];
#pragma unroll
  for (int i = 0; i < 4; ++i) {
    int d0 = i * 4096 + wid * 1024 + lane * 16;
    int co = d0 >> 7;
    swd[i]   = d0;
    swsrc[i] = co * 256 + ((d0 & 127) ^ ((co & 7) << 4));
  }
  const char* wt2c = (const char*)wt2;

  for (int chunk = 0; chunk < 2; ++chunk) {
    __syncthreads();
    if (tid < 192) {   // stage input rows h0-1..h0+1, 64 ci, f32 -> bf16 swizzled
      int rr = tid >> 6, cil = tid & 63;
      int ci = cil + chunk * 64;
      int h  = h0 + rr - 1;
      bool valid = (h >= 0) && (h < H);
      const float* src = in + (((size_t)b * CIN + ci) * H + (valid ? h : 0)) * W;
      int base = rr * 8448 + cil * 2;
#pragma unroll
      for (int j = 0; j < 16; ++j) {
        float4 v = valid ? *reinterpret_cast<const float4*>(src + j * 4)
                         : make_float4(0.f, 0.f, 0.f, 0.f);
        const float* ve = (const float*)&v;
#pragma unroll
        for (int e = 0; e < 4; ++e) {
          int wp = j * 4 + e + 1;
          int byte = (base + wp * 128) ^ ((wp & 7) << 4);
          *(unsigned short*)(sInc + byte) = f2bf(ve[e]);
        }
      }
    }

    for (int q = 0; q < 9; ++q) {
      if (q) __syncthreads();
      const char* wq = wt2c + q * (COUT * CIN * 2) + chunk * 128;
#pragma unroll
      for (int i = 0; i < 4; ++i)
        GLOAD_LDS16(wq + swsrc[i], sWc + swd[i]);
      __syncthreads();

      const int ky = q / 3, kx = q % 3;
#pragma unroll
      for (int ks = 0; ks < 2; ++ks) {
        const int cil2 = ks * 64 + kk * 16;
        short8 af[2];
#pragma unroll
        for (int m = 0; m < 2; ++m) {
          int wp = wave_px + m * 16 + l15 + kx;
          int byte = (ky * 8448 + wp * 128 + cil2) ^ ((wp & 7) << 4);
          af[m] = *(const short8*)(sInc + byte);
        }
        short8 bf[4];
#pragma unroll
        for (int n = 0; n < 4; ++n) {
          int co = wave_co + n * 16 + l15;
          int byte = (co * 128 + cil2) ^ ((co & 7) << 4);
          bf[n] = *(const short8*)(sWc + byte);
        }
#pragma unroll
        for (int m = 0; m < 2; ++m)
#pragma unroll
          for (int n = 0; n < 4; ++n)
            acc[m][n] = __builtin_amdgcn_mfma_f32_16x16x32_bf16(af[m], bf[n], acc[m][n], 0, 0, 0);
      }
    }
  }

  // epilogue: bias, bf16 round, write to the wave's half table (wave-uniform)
  unsigned short* tbl = (wave_co == 0) ? featA : featB;
  const size_t pbase = ((size_t)b * H + h0) * W;
#pragma unroll
  for (int m = 0; m < 2; ++m) {
#pragma unroll
    for (int r = 0; r < 4; ++r) {
      int px = wave_px + m * 16 + (lane >> 4) * 4 + r;
      unsigned short* dst = tbl + (pbase + px) * 64;
#pragma unroll
      for (int n = 0; n < 4; ++n)
        dst[n * 16 + l15] = f2bf(acc[m][n][r] + bv[n]);
    }
  }
}

// ---------------------------------------------------------------------------
// Pool over one channel half. One wave per point.
// lane = (pixel slot lane>>3 in 0..7, channel group lane&7 -> 8 bf16 = 16 B).
// Per gather instruction: 8 pixels x 64 ch = 8 rows x 128 B, coalesced.
// Gather table is 4.19 MB -> ~XCD-L2-resident; all single-use streams are
// nontemporal so they don't evict it. Tail pixels masked to bf16 -inf.
// ---------------------------------------------------------------------------
__global__ __launch_bounds__(256, 8)
void pool_half_kernel(const unsigned short* __restrict__ fhalf, const float* __restrict__ x3d,
                      const int* __restrict__ pix_idx, const int2* __restrict__ meta,
                      float* __restrict__ out, int N, int choff) {
  int n = blockIdx.x * 4 + (threadIdx.x >> 6);
  if (n >= N) return;
  const int lane = threadIdx.x & 63;
  const int slot = lane >> 3;     // 0..7 pixel slot
  const int l7   = lane & 7;      // channel group (8 ch, 16 B)

  const int2 mm = meta[n];
  const int p0 = mm.x;
  const int p1 = mm.y & 0x3FFFFFFF;
  const bool zfold = (mm.y & 0x40000000) != 0;

  // hoisted x3d read (nontemporal; slots 0..3 only — slot s owns ch l7*8+s*2,+1)
  const size_t obase = (size_t)n * COUT + choff + l7 * 8;
  float xv0 = 0.f, xv1 = 0.f;
  if (slot < 4) {
    unsigned long long xb =
        __builtin_nontemporal_load((const unsigned long long*)(x3d + obase + slot * 2));
    xv0 = ubits((unsigned)xb);
    xv1 = ubits((unsigned)(xb >> 32));
  }

  float acc[8];
#pragma unroll
  for (int j = 0; j < 8; ++j) acc[j] = -INFINITY;

  const char* fb = (const char*)fhalf + l7 * 16;
  const int last = p1 - 1;

  for (int g = p0; g < p1; g += 16) {
    int pp0 = g + slot, pp1 = g + 8 + slot;
    int i0 = __builtin_nontemporal_load(pix_idx + min(pp0, last));
    int i1 = __builtin_nontemporal_load(pix_idx + min(pp1, last));
    uint4 a = *reinterpret_cast<const uint4*>(fb + (size_t)i0 * 128);
    uint4 b = *reinterpret_cast<const uint4*>(fb + (size_t)i1 * 128);
    if (pp0 > last) { a.x = a.y = a.z = a.w = 0xFF80FF80u; }   // bf16 -inf pair
    if (pp1 > last) { b.x = b.y = b.z = b.w = 0xFF80FF80u; }
    const unsigned* aw = (const unsigned*)&a;
    const unsigned* bw = (const unsigned*)&b;
#pragma unroll
    for (int j = 0; j < 4; ++j) {
      acc[2*j]   = fmaxf(acc[2*j],   fmaxf(ubits(aw[j] << 16),         ubits(bw[j] << 16)));
      acc[2*j+1] = fmaxf(acc[2*j+1], fmaxf(ubits(aw[j] & 0xFFFF0000u), ubits(bw[j] & 0xFFFF0000u)));
    }
  }

  // reduce over the 8 pixel slots (lane bits 3..5)
#pragma unroll
  for (int j = 0; j < 8; ++j) {
    acc[j] = fmaxf(acc[j], __shfl_xor(acc[j], 8, 64));
    acc[j] = fmaxf(acc[j], __shfl_xor(acc[j], 16, 64));
    acc[j] = fmaxf(acc[j], __shfl_xor(acc[j], 32, 64));
  }
  if (zfold) {
#pragma unroll
    for (int j = 0; j < 8; ++j) acc[j] = fmaxf(acc[j], 0.f);
  }
  // p1==p0 => loop skipped, acc=-inf, zfold guaranteed true -> 0

  if (slot < 4) {
    union { float f[2]; unsigned long long u; } pk;
    pk.f[0] = xv0 + acc[slot * 2];
    pk.f[1] = xv1 + acc[slot * 2 + 1];
    __builtin_nontemporal_store(pk.u, (unsigned long long*)(out + obase + slot * 2));
  }
}

extern "C" void kernel_launch(void* const* d_in, const int* in_sizes, int n_in,
                              void* d_out, int out_size, void* d_ws, size_t ws_size,
                              hipStream_t stream) {
  const float* x3d     = (const float*)d_in[0];
  const float* mod_x   = (const float*)d_in[1];
  const float* conv_w  = (const float*)d_in[2];
  const float* conv_b  = (const float*)d_in[3];
  const int*   pix_idx = (const int*)d_in[4];
  const int*   aptr    = (const int*)d_in[5];
  const int*   vptr    = (const int*)d_in[6];
  float*       out     = (float*)d_out;

  int N = in_sizes[6] - 1;   // view_ptr has N+1 entries

  // ws layout: featA [32768][64] bf16 = 4194304 B; featB same; Wt2 294912 B; meta 400000 B
  unsigned short* featA = (unsigned short*)d_ws;
  unsigned short* featB = (unsigned short*)((char*)d_ws + 4194304);
  unsigned short* wt2   = (unsigned short*)((char*)d_ws + 8388608);
  int2*           meta  = (int2*)((char*)d_ws + 8388608 + 294912);

  prep_kernel<<<(N + 255) / 256, 256, 0, stream>>>(conv_w, wt2, aptr, vptr, meta, N);

  dim3 gc(64, 8);   // h0 x b
  conv_mfma_kernel<<<gc, 256, 0, stream>>>(mod_x, wt2, conv_b, featA, featB);

  int nblk = (N + 3) / 4;
  pool_half_kernel<<<nblk, 256, 0, stream>>>(featA, x3d, pix_idx, meta, out, N, 0);
  pool_half_kernel<<<nblk, 256, 0, stream>>>(featB, x3d, pix_idx, meta, out, N, 64);
}

// Round 7
// 73.998 us; speedup vs baseline: 1.3305x; 1.3305x over previous
//
#include <hip/hip_runtime.h>
#include <math.h>

// Problem constants: B=8, CIN=128, COUT=128, H=64, W=64, N=50000, NV=200000, M=800000
constexpr int CIN  = 128;
constexpr int COUT = 128;
constexpr int H    = 64;
constexpr int W    = 64;

typedef __attribute__((ext_vector_type(8))) short short8;   // 8 bf16 (4 VGPR)
typedef __attribute__((ext_vector_type(4))) float f32x4;

__device__ __forceinline__ float bf2f(unsigned short u) {
  union { unsigned i; float f; } c; c.i = (unsigned)u << 16; return c.f;
}
__device__ __forceinline__ float ubits(unsigned u) {
  union { unsigned i; float f; } c; c.i = u; return c.f;
}
__device__ __forceinline__ unsigned short f2bf(float f) {
  union { float f; unsigned i; } c; c.f = f;
  unsigned x = c.i;
  unsigned r = x + 0x7fffu + ((x >> 16) & 1u);   // RNE
  return (unsigned short)(r >> 16);
}

#define GLOAD_LDS16(g, l) __builtin_amdgcn_global_load_lds( \
  (const __attribute__((address_space(1))) unsigned int*)(g), \
  (__attribute__((address_space(3))) unsigned int*)(l), 16, 0, 0)

// ---------------------------------------------------------------------------
// Prep: (a) conv_w f32 [co][ci][3][3] -> Wt2 bf16 [q][co][ci] (k-major);
//       (b) per-point CSR meta: p0, p1, zero-fold flag
// ---------------------------------------------------------------------------
__global__ void prep_kernel(const float* __restrict__ w, unsigned short* __restrict__ wt2,
                            const int* __restrict__ aptr, const int* __restrict__ vptr,
                            int2* __restrict__ meta, int N) {
  int t = blockIdx.x * 256 + threadIdx.x;
  if (t < COUT * CIN) {
    float v[9];
#pragma unroll
    for (int q = 0; q < 9; ++q) v[q] = w[(size_t)t * 9 + q];
#pragma unroll
    for (int q = 0; q < 9; ++q) wt2[q * (COUT * CIN) + t] = f2bf(v[q]);
  }
  if (t < N) {
    int v0 = vptr[t], v1 = vptr[t + 1];
    int p0 = aptr[v0], p1 = aptr[v1];
    int e = (v1 == v0) ? 1 : 0;
    int prev = p0;
    for (int v = v0 + 1; v <= v1; ++v) {   // detect empty view segments
      int a = aptr[v];
      if (a == prev) e = 1;
      prev = a;
    }
    meta[t] = make_int2(p0, p1 | (e << 30));
  }
}

// ---------------------------------------------------------------------------
// Conv 3x3 SAME as implicit GEMM on MFMA bf16 (round-4 structure, single
// feat table [32768 px][128 co] bf16 = 8.39 MB).
// ---------------------------------------------------------------------------
__global__ __launch_bounds__(256, 2)
void conv_mfma_kernel(const float* __restrict__ in, const unsigned short* __restrict__ wt2,
                      const float* __restrict__ bias, unsigned short* __restrict__ feat) {
  __shared__ __align__(16) unsigned short sIn[3 * 66 * 64];  // 25344 B
  __shared__ __align__(16) unsigned short sW[128 * 64];      // 16384 B

  const int tid  = threadIdx.x;
  const int lane = tid & 63;
  const int wid  = tid >> 6;
  const int h0   = blockIdx.x;
  const int b    = blockIdx.y;
  const int wave_px = (wid >> 1) * 32;
  const int wave_co = (wid & 1) * 64;
  const int l15  = lane & 15;
  const int kk   = lane >> 4;

  char* sInc = (char*)sIn;
  char* sWc  = (char*)sW;

  f32x4 acc[2][4];
#pragma unroll
  for (int m = 0; m < 2; ++m)
#pragma unroll
    for (int n = 0; n < 4; ++n) acc[m][n] = (f32x4){0.f, 0.f, 0.f, 0.f};

  float bv[4];
#pragma unroll
  for (int n = 0; n < 4; ++n) bv[n] = bias[wave_co + n * 16 + l15];

  for (int i = tid; i < 3 * 64 * 2; i += 256) {   // zero pad columns wp=0,65
    int rr = i >> 7, rem = i & 127;
    int wp = (rem & 1) ? 65 : 0, ci = rem >> 1;
    int byte = rr * 8448 + wp * 128 + ci * 2;
    byte ^= ((wp & 7) << 4);
    *(unsigned short*)(sInc + byte) = 0;
  }

  int swd[4], swsrc[4];
#pragma unroll
  for (int i = 0; i < 4; ++i) {
    int d0 = i * 4096 + wid * 1024 + lane * 16;
    int co = d0 >> 7;
    swd[i]   = d0;
    swsrc[i] = co * 256 + ((d0 & 127) ^ ((co & 7) << 4));
  }
  const char* wt2c = (const char*)wt2;

  for (int chunk = 0; chunk < 2; ++chunk) {
    __syncthreads();
    if (tid < 192) {   // stage input rows h0-1..h0+1, 64 ci, f32 -> bf16 swizzled
      int rr = tid >> 6, cil = tid & 63;
      int ci = cil + chunk * 64;
      int h  = h0 + rr - 1;
      bool valid = (h >= 0) && (h < H);
      const float* src = in + (((size_t)b * CIN + ci) * H + (valid ? h : 0)) * W;
      int base = rr * 8448 + cil * 2;
#pragma unroll
      for (int j = 0; j < 16; ++j) {
        float4 v = valid ? *reinterpret_cast<const float4*>(src + j * 4)
                         : make_float4(0.f, 0.f, 0.f, 0.f);
        const float* ve = (const float*)&v;
#pragma unroll
        for (int e = 0; e < 4; ++e) {
          int wp = j * 4 + e + 1;
          int byte = (base + wp * 128) ^ ((wp & 7) << 4);
          *(unsigned short*)(sInc + byte) = f2bf(ve[e]);
        }
      }
    }

    for (int q = 0; q < 9; ++q) {
      if (q) __syncthreads();
      const char* wq = wt2c + q * (COUT * CIN * 2) + chunk * 128;
#pragma unroll
      for (int i = 0; i < 4; ++i)
        GLOAD_LDS16(wq + swsrc[i], sWc + swd[i]);
      __syncthreads();

      const int ky = q / 3, kx = q % 3;
#pragma unroll
      for (int ks = 0; ks < 2; ++ks) {
        const int cil2 = ks * 64 + kk * 16;
        short8 af[2];
#pragma unroll
        for (int m = 0; m < 2; ++m) {
          int wp = wave_px + m * 16 + l15 + kx;
          int byte = (ky * 8448 + wp * 128 + cil2) ^ ((wp & 7) << 4);
          af[m] = *(const short8*)(sInc + byte);
        }
        short8 bf[4];
#pragma unroll
        for (int n = 0; n < 4; ++n) {
          int co = wave_co + n * 16 + l15;
          int byte = (co * 128 + cil2) ^ ((co & 7) << 4);
          bf[n] = *(const short8*)(sWc + byte);
        }
#pragma unroll
        for (int m = 0; m < 2; ++m)
#pragma unroll
          for (int n = 0; n < 4; ++n)
            acc[m][n] = __builtin_amdgcn_mfma_f32_16x16x32_bf16(af[m], bf[n], acc[m][n], 0, 0, 0);
      }
    }
  }

  const size_t pbase = ((size_t)b * H + h0) * W;
#pragma unroll
  for (int m = 0; m < 2; ++m) {
#pragma unroll
    for (int r = 0; r < 4; ++r) {
      int px = wave_px + m * 16 + (lane >> 4) * 4 + r;
      unsigned short* dst = feat + (pbase + px) * COUT;
#pragma unroll
      for (int n = 0; n < 4; ++n) {
        int co = wave_co + n * 16 + l15;
        dst[co] = f2bf(acc[m][n][r] + bv[n]);
      }
    }
  }
}

// ---------------------------------------------------------------------------
// Pool: one wave per point, 4 pixel slots x 16 channel-groups (16 B/lane).
// 4-deep gather pipeline: 16 pixels (4 uint4 gathers) in flight per iteration
// to maximize outstanding L2 misses per wave. Tail pixels clamped to a valid
// row (cached) and masked to bf16 -inf. shfl_xor reduce over slots.
// ---------------------------------------------------------------------------
__global__ __launch_bounds__(256, 8)
void pool_kernel(const unsigned short* __restrict__ feat, const float* __restrict__ x3d,
                 const int* __restrict__ pix_idx, const int2* __restrict__ meta,
                 float* __restrict__ out, int N) {
  int n = blockIdx.x * 4 + (threadIdx.x >> 6);
  if (n >= N) return;
  const int lane = threadIdx.x & 63;
  const int slot = lane >> 4;     // 0..3 pixel slot
  const int l15  = lane & 15;     // channel group (8 ch = 16 B)

  const int2 mm = meta[n];
  const int p0 = mm.x;
  const int p1 = mm.y & 0x3FFFFFFF;
  const bool zfold = (mm.y & 0x40000000) != 0;

  // hoisted x3d prefetch (nontemporal, consumed at the very end)
  const size_t o = (size_t)n * COUT + l15 * 8 + slot * 2;
  unsigned long long xb =
      __builtin_nontemporal_load((const unsigned long long*)(x3d + o));

  float acc[8];
#pragma unroll
  for (int j = 0; j < 8; ++j) acc[j] = -INFINITY;

  const char* fb = (const char*)feat + l15 * 16;
  const int last = p1 - 1;

  for (int g = p0; g < p1; g += 16) {
    int pp[4];
    uint4 v[4];
#pragma unroll
    for (int u = 0; u < 4; ++u) {
      pp[u] = g + u * 4 + slot;
      int idx = __builtin_nontemporal_load(pix_idx + min(pp[u], last));
      v[u] = *reinterpret_cast<const uint4*>(fb + (size_t)idx * 256);
    }
#pragma unroll
    for (int u = 0; u < 4; ++u) {
      if (pp[u] > last) { v[u].x = v[u].y = v[u].z = v[u].w = 0xFF80FF80u; }  // bf16 -inf
      const unsigned* w = (const unsigned*)&v[u];
#pragma unroll
      for (int j = 0; j < 4; ++j) {
        acc[2*j]   = fmaxf(acc[2*j],   ubits(w[j] << 16));
        acc[2*j+1] = fmaxf(acc[2*j+1], ubits(w[j] & 0xFFFF0000u));
      }
    }
  }

  // reduce over the 4 pixel slots (lanes l15, l15+16, l15+32, l15+48)
#pragma unroll
  for (int j = 0; j < 8; ++j) {
    acc[j] = fmaxf(acc[j], __shfl_xor(acc[j], 16, 64));
    acc[j] = fmaxf(acc[j], __shfl_xor(acc[j], 32, 64));
  }
  if (zfold) {
#pragma unroll
    for (int j = 0; j < 8; ++j) acc[j] = fmaxf(acc[j], 0.f);
  }
  // p1==p0 => loop skipped, acc=-inf, zfold guaranteed true -> 0

  union { float f[2]; unsigned long long u; } pk;
  pk.f[0] = ubits((unsigned)xb)         + acc[slot * 2];
  pk.f[1] = ubits((unsigned)(xb >> 32)) + acc[slot * 2 + 1];
  __builtin_nontemporal_store(pk.u, (unsigned long long*)(out + o));
}

extern "C" void kernel_launch(void* const* d_in, const int* in_sizes, int n_in,
                              void* d_out, int out_size, void* d_ws, size_t ws_size,
                              hipStream_t stream) {
  const float* x3d     = (const float*)d_in[0];
  const float* mod_x   = (const float*)d_in[1];
  const float* conv_w  = (const float*)d_in[2];
  const float* conv_b  = (const float*)d_in[3];
  const int*   pix_idx = (const int*)d_in[4];
  const int*   aptr    = (const int*)d_in[5];
  const int*   vptr    = (const int*)d_in[6];
  float*       out     = (float*)d_out;

  int N = in_sizes[6] - 1;   // view_ptr has N+1 entries

  // ws layout: feat bf16 [32768][128] = 8388608 B; Wt2 bf16 294912 B; meta int2 400000 B
  unsigned short* feat = (unsigned short*)d_ws;
  unsigned short* wt2  = (unsigned short*)((char*)d_ws + 8388608);
  int2*           meta = (int2*)((char*)d_ws + 8388608 + 294912);

  prep_kernel<<<(N + 255) / 256, 256, 0, stream>>>(conv_w, wt2, aptr, vptr, meta, N);

  dim3 gc(64, 8);   // h0 x b
  conv_mfma_kernel<<<gc, 256, 0, stream>>>(mod_x, wt2, conv_b, feat);

  pool_kernel<<<(N + 3) / 4, 256, 0, stream>>>(feat, x3d, pix_idx, meta, out, N);
}